// Round 14
// baseline (72.588 us; speedup 1.0000x reference)
//
#include <hip/hip_runtime.h>

// x (64,3,512,512) f32, mean_params (64,4) f32.
#define BB 64
#define CC 3
#define HH 512
#define WW 512
#define HW (HH * WW)           // 262144
#define CHW (CC * HW)          // 786432

#define PROWS 64               // max staged rows (per-channel restage path)
#define PSTRIDE 68             // LDS row stride; 68 % 32 == 4 -> bank spread
#define SMEMF (PROWS * PSTRIDE) // 4352 floats = 17408 B

typedef float f2_t __attribute__((ext_vector_type(2), aligned(4)));
typedef float f4_t __attribute__((ext_vector_type(4), aligned(16)));

// Per-batch affine coefficients in PIXEL space: ix = ct*w - st*h + Cx
__global__ __launch_bounds__(64) void prep_kernel(const float* __restrict__ mp,
                                                  float4* __restrict__ cf)
{
    int b = threadIdx.x;
    if (b < BB) {
        float theta = mp[b * 4 + 0];
        float scale = mp[b * 4 + 1];
        float tx    = mp[b * 4 + 2];
        float ty    = mp[b * 4 + 3];
        float s, c;
        sincosf(theta, &s, &c);
        float ct = scale * c;
        float st = scale * s;
        const float d = -255.5f;                 // 256*xs at w=0
        float Cx = d * (ct - st) + 256.0f * tx + 255.5f;
        float Cy = d * (st + ct) + 256.0f * ty + 255.5f;
        cf[b] = make_float4(ct, st, Cx, Cy);
    }
}

// 4-way block-uniform classification (R13) + interior VALU trim (R14):
//  OOB      -> store zeros, return
//  compact  -> ALL 3 channels staged at once, ONE barrier
//  staged   -> per-channel restage (5 barriers)
//  fallback -> direct global f2 gathers
// interior blocks use lerp-form blend (6 VALU/px/ch vs 8), no clamps, no o1[].
__global__ __launch_bounds__(256, 8) void affine_sample_kernel(
    const float* __restrict__ x,
    const float4* __restrict__ cf,
    float* __restrict__ out)
{
    __shared__ float smem[SMEMF];                // 17408 B -> 8 blocks/CU

    int tid  = threadIdx.x;
    int lane = tid & 63;
    int wid  = tid >> 6;
    int strip = lane & 7;
    int lrow  = lane >> 3;

    int bidx = blockIdx.x;          // [b:6][tile:8]
    int b    = bidx >> 8;
    int rem  = bidx & 255;
    int tileH = (rem >> 4) << 5;
    int tileW = (rem & 15) << 5;

    int h  = tileH + (wid << 3) + lrow;
    int w0 = tileW + (strip << 2);

    float4 k = cf[b];
    float ct = k.x, st = k.y, Cx = k.z, Cy = k.w;

    // ---- block-uniform source bbox from tile corners
    float wA = (float)tileW, wB = (float)(tileW + 31);
    float hA = (float)tileH, hB = (float)(tileH + 31);
    float cwA = ct * wA, cwB = ct * wB, shA = st * hA, shB = st * hB;
    float ixmin = fminf(cwA, cwB) - fmaxf(shA, shB) + Cx;
    float ixmax = fmaxf(cwA, cwB) - fminf(shA, shB) + Cx;
    float swA = st * wA, swB = st * wB, chA = ct * hA, chB = ct * hB;
    float iymin = fminf(swA, swB) + fminf(chA, chB) + Cy;
    float iymax = fmaxf(swA, swB) + fmaxf(chA, chB) + Cy;

    int bx_lo = (int)floorf(ixmin) - 1;          // +-1: ulp-drift margin
    int bx_hi = (int)floorf(ixmax) + 2;
    int by_lo = (int)floorf(iymin) - 1;
    int by_hi = (int)floorf(iymax) + 2;

    float* ob = out + b * CHW + h * WW + w0;

    // ---- class 1: fully out-of-bounds -> exact zeros
    bool oob = (bx_hi <= 0) | (bx_lo >= WW - 1) | (by_hi <= 0) | (by_lo >= HH - 1);
    if (oob) {
        const f4_t z = {0.0f, 0.0f, 0.0f, 0.0f};
#pragma unroll
        for (int ch = 0; ch < CC; ++ch)
            __builtin_nontemporal_store(z, (f4_t*)(ob + ch * HW));
        return;
    }

    // ---- interior modifier: all corners valid, clamps dead
    bool interior = (bx_lo >= 0) & (bx_hi <= WW - 1) & (by_lo >= 0) & (by_hi <= HH - 1);

    int px_lo = min(max(bx_lo, 0), WW - 2);
    int px_hi = min(max(bx_hi - 1, 0), WW - 2) + 1;
    int py_lo = min(max(by_lo, 0), HH - 2);
    int py_hi = min(max(by_hi - 1, 0), HH - 2) + 1;
    int By = py_hi - py_lo + 1;

    int ax_lo = px_lo & ~3;                      // 16B-aligned window start
    int span  = px_hi - ax_lo;                   // cols needed minus 1
    bool staged = (span <= 63) && (By <= PROWS);
    int BxA = (span | 3) + 1;                    // tight width, mult of 4, <=64
    if (ax_lo + BxA > WW) ax_lo = WW - BxA;      // keep window in-bounds (aligned)

    // compact: all 3 channels fit in LDS at once -> single barrier
    int SSTR = BxA + 4;                          // mult of 4, != 0 mod 32 spread
    int cpc  = By * SSTR;                        // floats per channel
    bool compact = staged && (3 * cpc <= SMEMF);
    int lstr = compact ? SSTR : PSTRIDE;

    const float* plane0 = x + b * CHW;
    const float* srcb   = plane0 + py_lo * WW + ax_lo;

    int r0 = tid >> 4;                           // 0..15 staging row
    int c4 = (tid & 15) << 2;                    // 0,4,...,60 staging col

    bool cok = c4 < BxA;                         // tight width guard
    bool g0 = cok & (r0      < By);
    bool g1 = cok & (r0 + 16 < By);
    bool g2 = cok & (r0 + 32 < By);
    bool g3 = cok & (r0 + 48 < By);

    // burst staging: 4 loads in flight, then 4 ds_writes; temps die here
    auto burst = [&](const float* s, float* dst, int stride) {
        f4_t t0 = {0,0,0,0}, t1 = {0,0,0,0}, t2 = {0,0,0,0}, t3 = {0,0,0,0};
        if (g0) t0 = *(const f4_t*)(s +  r0       * WW + c4);
        if (g1) t1 = *(const f4_t*)(s + (r0 + 16) * WW + c4);
        if (g2) t2 = *(const f4_t*)(s + (r0 + 32) * WW + c4);
        if (g3) t3 = *(const f4_t*)(s + (r0 + 48) * WW + c4);
        if (g0) *(f4_t*)(dst +  r0       * stride + c4) = t0;
        if (g1) *(f4_t*)(dst + (r0 + 16) * stride + c4) = t1;
        if (g2) *(f4_t*)(dst + (r0 + 32) * stride + c4) = t2;
        if (g3) *(f4_t*)(dst + (r0 + 48) * stride + c4) = t3;
    };

    // ---- per-pixel geometry (incremental along the 4-px strip; shared by 3 ch)
    float ix = ct * (float)w0 - st * (float)h + Cx;
    float iy = st * (float)w0 + ct * (float)h + Cy;

    float fx[4], fy[4];                 // interior (lerp) form
    float al[4], ar[4], f0[4], f1[4];   // general (mask-folded) form
    int o0[4], o1[4];

    if (interior) {
        // coords provably >= 0: (int) trunc == floor; y1=y0+1 valid -> no o1
#pragma unroll
        for (int p = 0; p < 4; ++p) {
            int x0 = (int)ix, y0 = (int)iy;
            fx[p] = ix - (float)x0;
            fy[p] = iy - (float)y0;
            o0[p] = staged ? (y0 - py_lo) * lstr + (x0 - ax_lo)
                           :  y0 * WW + x0;
            ix += ct;
            iy += st;
        }
    } else {
#pragma unroll
        for (int p = 0; p < 4; ++p) {
            float x0f = floorf(ix), y0f = floorf(iy);
            float ffx = ix - x0f,   ffy = iy - y0f;
            int x0 = (int)x0f, y0 = (int)y0f;
            int y1 = y0 + 1;

            bool xin = (x0 >= 0) & (x0 <= WW - 2);
            float wl = 1.0f - ffx;
            al[p] = xin ? wl  : ((x0 == -1)     ? ffx : 0.0f);
            ar[p] = xin ? ffx : ((x0 == WW - 1) ? wl  : 0.0f);
            int base = min(max(x0, 0), WW - 2);

            bool vy0 = (y0 >= 0) & (y0 < HH);
            bool vy1 = (y1 >= 0) & (y1 < HH);
            int y0c = min(max(y0, 0), HH - 1);
            int y1c = min(max(y1, 0), HH - 1);
            f0[p] = (1.0f - ffy) * (float)vy0;
            f1[p] = ffy          * (float)vy1;

            if (staged) {
                int lx = base - ax_lo;
                o0[p] = (y0c - py_lo) * lstr + lx;
                o1[p] = (y1c - py_lo) * lstr + lx;
            } else {
                o0[p] = y0c * WW + base;
                o1[p] = y1c * WW + base;
            }
            ix += ct;
            iy += st;
        }
    }

    // LDS blend: lerp form for interior, coeff form otherwise
    auto blendL = [&](const float* pl, int stride, int ch) {
        f4_t v;
        if (interior) {
#pragma unroll
            for (int p = 0; p < 4; ++p) {
                float a0 = pl[o0[p]],          a1 = pl[o0[p] + 1];
                float b0 = pl[o0[p] + stride], b1 = pl[o0[p] + stride + 1];
                float tp = a0 + fx[p] * (a1 - a0);
                float bt = b0 + fx[p] * (b1 - b0);
                v[p] = tp + fy[p] * (bt - tp);
            }
        } else {
#pragma unroll
            for (int p = 0; p < 4; ++p) {
                float a0 = pl[o0[p]], a1 = pl[o0[p] + 1];
                float b0 = pl[o1[p]], b1 = pl[o1[p] + 1];
                v[p] = f0[p] * (al[p] * a0 + ar[p] * a1)
                     + f1[p] * (al[p] * b0 + ar[p] * b1);
            }
        }
        __builtin_nontemporal_store(v, (f4_t*)(ob + ch * HW));
    };

    if (compact) {
        // stage ALL 3 channels, one barrier, blend with no further syncs
        burst(srcb,          &smem[0],       SSTR);
        burst(srcb + HW,     &smem[cpc],     SSTR);
        burst(srcb + 2 * HW, &smem[2 * cpc], SSTR);
        __syncthreads();
#pragma unroll
        for (int ch = 0; ch < CC; ++ch)
            blendL(&smem[ch * cpc], SSTR, ch);
    } else if (staged) {
        // per-channel restage (bbox too big for 3-at-once)
#pragma unroll
        for (int ch = 0; ch < CC; ++ch) {
            if (ch) __syncthreads();             // previous blend's reads done
            burst(srcb + ch * HW, smem, PSTRIDE);
            __syncthreads();                     // patch ready
            blendL(smem, PSTRIDE, ch);
        }
    } else {
        // fallback: direct global f2 gathers (large scale, no barriers)
#pragma unroll
        for (int ch = 0; ch < CC; ++ch) {
            const float* pl = plane0 + ch * HW;
            f4_t v;
            if (interior) {
#pragma unroll
                for (int p = 0; p < 4; ++p) {
                    f2_t t = *(const f2_t*)(pl + o0[p]);
                    f2_t u = *(const f2_t*)(pl + o0[p] + WW);
                    float tp = t.x + fx[p] * (t.y - t.x);
                    float bt = u.x + fx[p] * (u.y - u.x);
                    v[p] = tp + fy[p] * (bt - tp);
                }
            } else {
#pragma unroll
                for (int p = 0; p < 4; ++p) {
                    f2_t t = *(const f2_t*)(pl + o0[p]);
                    f2_t u = *(const f2_t*)(pl + o1[p]);
                    v[p] = f0[p] * (al[p] * t.x + ar[p] * t.y)
                         + f1[p] * (al[p] * u.x + ar[p] * u.y);
                }
            }
            __builtin_nontemporal_store(v, (f4_t*)(ob + ch * HW));
        }
    }
}

extern "C" void kernel_launch(void* const* d_in, const int* in_sizes, int n_in,
                              void* d_out, int out_size, void* d_ws, size_t ws_size,
                              hipStream_t stream)
{
    const float* x  = (const float*)d_in[0];
    const float* mp = (const float*)d_in[1];
    float* out = (float*)d_out;
    float4* cf = (float4*)d_ws;     // 1 KB scratch

    prep_kernel<<<1, 64, 0, stream>>>(mp, cf);
    dim3 block(256);
    dim3 grid(BB * 256);            // 64 batches x 16x16 tiles of 32x32
    affine_sample_kernel<<<grid, block, 0, stream>>>(x, cf, out);
}

// Round 15
// 52.905 us; speedup vs baseline: 1.3720x; 1.3720x over previous
//
#include <hip/hip_runtime.h>

// x (64,3,512,512) f32, mean_params (64,4) f32.
#define BB 64
#define CC 3
#define HH 512
#define WW 512
#define HW (HH * WW)           // 262144
#define CHW (CC * HW)          // 786432

#define PROWS 64               // max staged rows
#define PSTRIDE 68             // LDS row stride; 68 % 32 == 4 -> bank spread
#define SMEMF (PROWS * PSTRIDE) // 4352 floats = 17408 B

typedef float f2_t __attribute__((ext_vector_type(2), aligned(4)));
typedef float f4_t __attribute__((ext_vector_type(4), aligned(16)));

// Per-batch affine coefficients in PIXEL space: ix = ct*w - st*h + Cx
__global__ __launch_bounds__(64) void prep_kernel(const float* __restrict__ mp,
                                                  float4* __restrict__ cf)
{
    int b = threadIdx.x;
    if (b < BB) {
        float theta = mp[b * 4 + 0];
        float scale = mp[b * 4 + 1];
        float tx    = mp[b * 4 + 2];
        float ty    = mp[b * 4 + 3];
        float s, c;
        sincosf(theta, &s, &c);
        float ct = scale * c;
        float st = scale * s;
        const float d = -255.5f;                 // 256*xs at w=0
        float Cx = d * (ct - st) + 256.0f * tx + 255.5f;
        float Cy = d * (st + ct) + 256.0f * ty + 255.5f;
        cf[b] = make_float4(ct, st, Cx, Cy);
    }
}

// Classification (all block-uniform):
//  OOB            -> zeros, return
//  staged 32x32   -> R13 compact / per-channel restage (unchanged champion)
//  else           -> 4x 16x16 SUB-TILES: per-subtile {oob-zero | stage+blend |
//                    f2 gather}; covers scale up to ~2.8 with LDS staging.
__global__ __launch_bounds__(256, 8) void affine_sample_kernel(
    const float* __restrict__ x,
    const float4* __restrict__ cf,
    float* __restrict__ out)
{
    __shared__ float smem[SMEMF];                // 17408 B -> 8 blocks/CU

    int tid  = threadIdx.x;
    int lane = tid & 63;
    int wid  = tid >> 6;
    int strip = lane & 7;
    int lrow  = lane >> 3;

    int bidx = blockIdx.x;          // [b:6][tile:8]
    int b    = bidx >> 8;
    int rem  = bidx & 255;
    int tileH = (rem >> 4) << 5;
    int tileW = (rem & 15) << 5;

    int h  = tileH + (wid << 3) + lrow;
    int w0 = tileW + (strip << 2);

    float4 k = cf[b];
    float ct = k.x, st = k.y, Cx = k.z, Cy = k.w;

    // ---- full-tile bbox from corners
    float wA = (float)tileW, wB = (float)(tileW + 31);
    float hA = (float)tileH, hB = (float)(tileH + 31);
    float cwA = ct * wA, cwB = ct * wB, shA = st * hA, shB = st * hB;
    float ixmin = fminf(cwA, cwB) - fmaxf(shA, shB) + Cx;
    float ixmax = fmaxf(cwA, cwB) - fminf(shA, shB) + Cx;
    float swA = st * wA, swB = st * wB, chA = ct * hA, chB = ct * hB;
    float iymin = fminf(swA, swB) + fminf(chA, chB) + Cy;
    float iymax = fmaxf(swA, swB) + fmaxf(chA, chB) + Cy;

    int bx_lo = (int)floorf(ixmin) - 1;          // +-1: ulp-drift margin
    int bx_hi = (int)floorf(ixmax) + 2;
    int by_lo = (int)floorf(iymin) - 1;
    int by_hi = (int)floorf(iymax) + 2;

    float* ob = out + b * CHW + h * WW + w0;

    // ---- class 1: fully out-of-bounds -> exact zeros
    bool oob = (bx_hi <= 0) | (bx_lo >= WW - 1) | (by_hi <= 0) | (by_lo >= HH - 1);
    if (oob) {
        const f4_t z = {0.0f, 0.0f, 0.0f, 0.0f};
#pragma unroll
        for (int ch = 0; ch < CC; ++ch)
            __builtin_nontemporal_store(z, (f4_t*)(ob + ch * HW));
        return;
    }

    bool interior = (bx_lo >= 0) & (bx_hi <= WW - 1) & (by_lo >= 0) & (by_hi <= HH - 1);

    int px_lo = min(max(bx_lo, 0), WW - 2);
    int px_hi = min(max(bx_hi - 1, 0), WW - 2) + 1;
    int py_lo = min(max(by_lo, 0), HH - 2);
    int py_hi = min(max(by_hi - 1, 0), HH - 2) + 1;
    int By = py_hi - py_lo + 1;

    int ax_lo = px_lo & ~3;
    int span  = px_hi - ax_lo;
    bool staged = (span <= 63) && (By <= PROWS);

    const float* plane0 = x + b * CHW;

    if (staged) {
        // ================= R13 champion path, unchanged =================
        int BxA = (span | 3) + 1;
        if (ax_lo + BxA > WW) ax_lo = WW - BxA;
        int SSTR = BxA + 4;
        int cpc  = By * SSTR;
        bool compact = (3 * cpc <= SMEMF);
        int lstr = compact ? SSTR : PSTRIDE;

        const float* srcb = plane0 + py_lo * WW + ax_lo;
        int r0 = tid >> 4;
        int c4 = (tid & 15) << 2;
        bool cok = c4 < BxA;
        bool g0 = cok & (r0      < By);
        bool g1 = cok & (r0 + 16 < By);
        bool g2 = cok & (r0 + 32 < By);
        bool g3 = cok & (r0 + 48 < By);

        auto burst = [&](const float* s, float* dst, int stride) {
            f4_t t0 = {0,0,0,0}, t1 = {0,0,0,0}, t2 = {0,0,0,0}, t3 = {0,0,0,0};
            if (g0) t0 = *(const f4_t*)(s +  r0       * WW + c4);
            if (g1) t1 = *(const f4_t*)(s + (r0 + 16) * WW + c4);
            if (g2) t2 = *(const f4_t*)(s + (r0 + 32) * WW + c4);
            if (g3) t3 = *(const f4_t*)(s + (r0 + 48) * WW + c4);
            if (g0) *(f4_t*)(dst +  r0       * stride + c4) = t0;
            if (g1) *(f4_t*)(dst + (r0 + 16) * stride + c4) = t1;
            if (g2) *(f4_t*)(dst + (r0 + 32) * stride + c4) = t2;
            if (g3) *(f4_t*)(dst + (r0 + 48) * stride + c4) = t3;
        };

        float ix = ct * (float)w0 - st * (float)h + Cx;
        float iy = st * (float)w0 + ct * (float)h + Cy;

        float al[4], ar[4], f0[4], f1[4];
        int o0[4], o1[4];

        if (interior) {
#pragma unroll
            for (int p = 0; p < 4; ++p) {
                float x0f = floorf(ix), y0f = floorf(iy);
                float fx = ix - x0f,    fy = iy - y0f;
                int x0 = (int)x0f, y0 = (int)y0f;
                al[p] = 1.0f - fx;
                ar[p] = fx;
                f0[p] = 1.0f - fy;
                f1[p] = fy;
                int lx = x0 - ax_lo;
                o0[p] = (y0     - py_lo) * lstr + lx;
                o1[p] = (y0 + 1 - py_lo) * lstr + lx;
                ix += ct;
                iy += st;
            }
        } else {
#pragma unroll
            for (int p = 0; p < 4; ++p) {
                float x0f = floorf(ix), y0f = floorf(iy);
                float fx = ix - x0f,    fy = iy - y0f;
                int x0 = (int)x0f, y0 = (int)y0f;
                int y1 = y0 + 1;

                bool xin = (x0 >= 0) & (x0 <= WW - 2);
                float wl = 1.0f - fx;
                al[p] = xin ? wl : ((x0 == -1)     ? fx : 0.0f);
                ar[p] = xin ? fx : ((x0 == WW - 1) ? wl : 0.0f);
                int base = min(max(x0, 0), WW - 2);

                bool vy0 = (y0 >= 0) & (y0 < HH);
                bool vy1 = (y1 >= 0) & (y1 < HH);
                int y0c = min(max(y0, 0), HH - 1);
                int y1c = min(max(y1, 0), HH - 1);
                f0[p] = (1.0f - fy) * (float)vy0;
                f1[p] = fy          * (float)vy1;

                int lx = base - ax_lo;
                o0[p] = (y0c - py_lo) * lstr + lx;
                o1[p] = (y1c - py_lo) * lstr + lx;
                ix += ct;
                iy += st;
            }
        }

        if (compact) {
            burst(srcb,          &smem[0],       SSTR);
            burst(srcb + HW,     &smem[cpc],     SSTR);
            burst(srcb + 2 * HW, &smem[2 * cpc], SSTR);
            __syncthreads();
#pragma unroll
            for (int ch = 0; ch < CC; ++ch) {
                const float* pl = &smem[ch * cpc];
                f4_t v;
#pragma unroll
                for (int p = 0; p < 4; ++p) {
                    float a0 = pl[o0[p]], a1 = pl[o0[p] + 1];
                    float b0 = pl[o1[p]], b1 = pl[o1[p] + 1];
                    v[p] = f0[p] * (al[p] * a0 + ar[p] * a1)
                         + f1[p] * (al[p] * b0 + ar[p] * b1);
                }
                __builtin_nontemporal_store(v, (f4_t*)(ob + ch * HW));
            }
        } else {
#pragma unroll
            for (int ch = 0; ch < CC; ++ch) {
                if (ch) __syncthreads();
                burst(srcb + ch * HW, smem, PSTRIDE);
                __syncthreads();

                f4_t v;
#pragma unroll
                for (int p = 0; p < 4; ++p) {
                    float a0 = smem[o0[p]], a1 = smem[o0[p] + 1];
                    float b0 = smem[o1[p]], b1 = smem[o1[p] + 1];
                    v[p] = f0[p] * (al[p] * a0 + ar[p] * a1)
                         + f1[p] * (al[p] * b0 + ar[p] * b1);
                }
                __builtin_nontemporal_store(v, (f4_t*)(ob + ch * HW));
            }
        }
        return;
    }

    // ================= SUB-TILE path (large scale) =================
    // Four 16x16 sub-tiles; each: oob-zero | per-channel LDS stage | f2 gather.
    int rS = tid >> 4;              // 0..15: blend row, staging row base
    int cS = tid & 15;              // 0..15: blend col
    int c4 = cS << 2;               // staging col (floats)

#pragma unroll 1
    for (int s = 0; s < 4; ++s) {
        int sW = tileW + ((s & 1) << 4);
        int sH = tileH + ((s >> 1) << 4);

        // sub-tile bbox from corners
        float wAs = (float)sW, wBs = (float)(sW + 15);
        float hAs = (float)sH, hBs = (float)(sH + 15);
        float cwAs = ct * wAs, cwBs = ct * wBs, shAs = st * hAs, shBs = st * hBs;
        float ixmn = fminf(cwAs, cwBs) - fmaxf(shAs, shBs) + Cx;
        float ixmx = fmaxf(cwAs, cwBs) - fminf(shAs, shBs) + Cx;
        float swAs = st * wAs, swBs = st * wBs, chAs = ct * hAs, chBs = ct * hBs;
        float iymn = fminf(swAs, swBs) + fminf(chAs, chBs) + Cy;
        float iymx = fmaxf(swAs, swBs) + fmaxf(chAs, chBs) + Cy;

        int bxl = (int)floorf(ixmn) - 1;
        int bxh = (int)floorf(ixmx) + 2;
        int byl = (int)floorf(iymn) - 1;
        int byh = (int)floorf(iymx) + 2;

        int ws = sW + cS;           // this thread's output pixel
        int hs = sH + rS;
        float* ob2 = out + b * CHW + hs * WW + ws;

        bool oob_s = (bxh <= 0) | (bxl >= WW - 1) | (byh <= 0) | (byl >= HH - 1);
        if (oob_s) {
#pragma unroll
            for (int ch = 0; ch < CC; ++ch)
                __builtin_nontemporal_store(0.0f, ob2 + ch * HW);
            continue;
        }

        int pxl = min(max(bxl, 0), WW - 2);
        int pxh = min(max(bxh - 1, 0), WW - 2) + 1;
        int pyl = min(max(byl, 0), HH - 2);
        int pyh = min(max(byh - 1, 0), HH - 2) + 1;
        int Bys = pyh - pyl + 1;

        int axl = pxl & ~3;
        int spn = pxh - axl;
        bool subok = (spn <= 63) && (Bys <= PROWS);
        int BxS = (spn | 3) + 1;
        if (axl + BxS > WW) axl = WW - BxS;

        // scalar per-px geometry (general mask-folded form)
        float ixs = ct * (float)ws - st * (float)hs + Cx;
        float iys = st * (float)ws + ct * (float)hs + Cy;
        float x0f = floorf(ixs), y0f = floorf(iys);
        float fxs = ixs - x0f,   fys = iys - y0f;
        int x0 = (int)x0f, y0 = (int)y0f;
        int y1 = y0 + 1;

        bool xin = (x0 >= 0) & (x0 <= WW - 2);
        float wl = 1.0f - fxs;
        float alS = xin ? wl  : ((x0 == -1)     ? fxs : 0.0f);
        float arS = xin ? fxs : ((x0 == WW - 1) ? wl  : 0.0f);
        int base = min(max(x0, 0), WW - 2);

        bool vy0 = (y0 >= 0) & (y0 < HH);
        bool vy1 = (y1 >= 0) & (y1 < HH);
        int y0c = min(max(y0, 0), HH - 1);
        int y1c = min(max(y1, 0), HH - 1);
        float f0S = (1.0f - fys) * (float)vy0;
        float f1S = fys          * (float)vy1;

        if (subok) {
            int lx  = base - axl;
            int os0 = (y0c - pyl) * PSTRIDE + lx;
            int os1 = (y1c - pyl) * PSTRIDE + lx;
            const float* sb = plane0 + pyl * WW + axl;

            bool cokS = c4 < BxS;
            bool h0 = cokS & (rS      < Bys);
            bool h1 = cokS & (rS + 16 < Bys);
            bool h2 = cokS & (rS + 32 < Bys);
            bool h3 = cokS & (rS + 48 < Bys);

            for (int ch = 0; ch < CC; ++ch) {
                __syncthreads();             // protect any prior smem reads
                {
                    const float* ss = sb + ch * HW;
                    f4_t t0 = {0,0,0,0}, t1 = {0,0,0,0}, t2 = {0,0,0,0}, t3 = {0,0,0,0};
                    if (h0) t0 = *(const f4_t*)(ss +  rS       * WW + c4);
                    if (h1) t1 = *(const f4_t*)(ss + (rS + 16) * WW + c4);
                    if (h2) t2 = *(const f4_t*)(ss + (rS + 32) * WW + c4);
                    if (h3) t3 = *(const f4_t*)(ss + (rS + 48) * WW + c4);
                    if (h0) *(f4_t*)(&smem[ rS       * PSTRIDE + c4]) = t0;
                    if (h1) *(f4_t*)(&smem[(rS + 16) * PSTRIDE + c4]) = t1;
                    if (h2) *(f4_t*)(&smem[(rS + 32) * PSTRIDE + c4]) = t2;
                    if (h3) *(f4_t*)(&smem[(rS + 48) * PSTRIDE + c4]) = t3;
                }
                __syncthreads();             // patch ready

                float a0 = smem[os0], a1 = smem[os0 + 1];
                float b0 = smem[os1], b1 = smem[os1 + 1];
                float v = f0S * (alS * a0 + arS * a1)
                        + f1S * (alS * b0 + arS * b1);
                __builtin_nontemporal_store(v, ob2 + ch * HW);
            }
        } else {
            // ultra-rare (scale > ~2.8): direct f2 gathers
            int og0 = y0c * WW + base;
            int og1 = y1c * WW + base;
#pragma unroll
            for (int ch = 0; ch < CC; ++ch) {
                const float* pl = plane0 + ch * HW;
                f2_t t = *(const f2_t*)(pl + og0);
                f2_t u = *(const f2_t*)(pl + og1);
                float v = f0S * (alS * t.x + arS * t.y)
                        + f1S * (alS * u.x + arS * u.y);
                __builtin_nontemporal_store(v, ob2 + ch * HW);
            }
        }
    }
}

extern "C" void kernel_launch(void* const* d_in, const int* in_sizes, int n_in,
                              void* d_out, int out_size, void* d_ws, size_t ws_size,
                              hipStream_t stream)
{
    const float* x  = (const float*)d_in[0];
    const float* mp = (const float*)d_in[1];
    float* out = (float*)d_out;
    float4* cf = (float4*)d_ws;     // 1 KB scratch

    prep_kernel<<<1, 64, 0, stream>>>(mp, cf);
    dim3 block(256);
    dim3 grid(BB * 256);            // 64 batches x 16x16 tiles of 32x32
    affine_sample_kernel<<<grid, block, 0, stream>>>(x, cf, out);
}

// Round 16
// 48.236 us; speedup vs baseline: 1.5049x; 1.0968x over previous
//
#include <hip/hip_runtime.h>

// x (64,3,512,512) f32, mean_params (64,4) f32.
#define BB 64
#define CC 3
#define HH 512
#define WW 512
#define HW (HH * WW)           // 262144
#define CHW (CC * HW)          // 786432

#define PROWS 64               // max staged rows
#define PSTRIDE 68             // LDS row stride; 68 % 32 == 4 -> bank spread
#define SMEMF (PROWS * PSTRIDE) // 4352 floats = 17408 B

typedef float f2_t __attribute__((ext_vector_type(2), aligned(4)));
typedef float f4_t __attribute__((ext_vector_type(4), aligned(16)));

// R15 champion structure, single change: prep kernel ELIMINATED. Affine
// coefficients computed per thread with HW trig (v_sin_f32/v_cos_f32 via
// __sinf/__cosf, ~10cyc) instead of a serial 1-block prep launch (~2-4us
// of whole-device idle per graph replay). Trig error ~1e-6 -> dix ~2e-3 px;
// bilinear+zero-pad is continuous in (ix,iy) -> absmax stays << threshold.
__global__ __launch_bounds__(256, 8) void affine_sample_kernel(
    const float* __restrict__ x,
    const float* __restrict__ mp,
    float* __restrict__ out)
{
    __shared__ float smem[SMEMF];                // 17408 B -> 8 blocks/CU

    int tid  = threadIdx.x;
    int lane = tid & 63;
    int wid  = tid >> 6;
    int strip = lane & 7;
    int lrow  = lane >> 3;

    int bidx = blockIdx.x;          // [b:6][tile:8]
    int b    = bidx >> 8;
    int rem  = bidx & 255;
    int tileH = (rem >> 4) << 5;
    int tileW = (rem & 15) << 5;

    int h  = tileH + (wid << 3) + lrow;
    int w0 = tileW + (strip << 2);

    // ---- per-batch affine coefficients in PIXEL space (inline, HW trig)
    const float4 mpb = ((const float4*)mp)[b];   // theta, scale, tx, ty
    float cs = __cosf(mpb.x);
    float sn = __sinf(mpb.x);
    float ct = mpb.y * cs;
    float st = mpb.y * sn;
    const float dd = -255.5f;                    // 256*xs at w=0
    float Cx = dd * (ct - st) + 256.0f * mpb.z + 255.5f;
    float Cy = dd * (st + ct) + 256.0f * mpb.w + 255.5f;

    // ---- full-tile bbox from corners
    float wA = (float)tileW, wB = (float)(tileW + 31);
    float hA = (float)tileH, hB = (float)(tileH + 31);
    float cwA = ct * wA, cwB = ct * wB, shA = st * hA, shB = st * hB;
    float ixmin = fminf(cwA, cwB) - fmaxf(shA, shB) + Cx;
    float ixmax = fmaxf(cwA, cwB) - fminf(shA, shB) + Cx;
    float swA = st * wA, swB = st * wB, chA = ct * hA, chB = ct * hB;
    float iymin = fminf(swA, swB) + fminf(chA, chB) + Cy;
    float iymax = fmaxf(swA, swB) + fmaxf(chA, chB) + Cy;

    int bx_lo = (int)floorf(ixmin) - 1;          // +-1: ulp-drift margin
    int bx_hi = (int)floorf(ixmax) + 2;
    int by_lo = (int)floorf(iymin) - 1;
    int by_hi = (int)floorf(iymax) + 2;

    float* ob = out + b * CHW + h * WW + w0;

    // ---- class 1: fully out-of-bounds -> exact zeros
    bool oob = (bx_hi <= 0) | (bx_lo >= WW - 1) | (by_hi <= 0) | (by_lo >= HH - 1);
    if (oob) {
        const f4_t z = {0.0f, 0.0f, 0.0f, 0.0f};
#pragma unroll
        for (int ch = 0; ch < CC; ++ch)
            __builtin_nontemporal_store(z, (f4_t*)(ob + ch * HW));
        return;
    }

    bool interior = (bx_lo >= 0) & (bx_hi <= WW - 1) & (by_lo >= 0) & (by_hi <= HH - 1);

    int px_lo = min(max(bx_lo, 0), WW - 2);
    int px_hi = min(max(bx_hi - 1, 0), WW - 2) + 1;
    int py_lo = min(max(by_lo, 0), HH - 2);
    int py_hi = min(max(by_hi - 1, 0), HH - 2) + 1;
    int By = py_hi - py_lo + 1;

    int ax_lo = px_lo & ~3;
    int span  = px_hi - ax_lo;
    bool staged = (span <= 63) && (By <= PROWS);

    const float* plane0 = x + b * CHW;

    if (staged) {
        // ================= R13 champion path =================
        int BxA = (span | 3) + 1;
        if (ax_lo + BxA > WW) ax_lo = WW - BxA;
        int SSTR = BxA + 4;
        int cpc  = By * SSTR;
        bool compact = (3 * cpc <= SMEMF);
        int lstr = compact ? SSTR : PSTRIDE;

        const float* srcb = plane0 + py_lo * WW + ax_lo;
        int r0 = tid >> 4;
        int c4 = (tid & 15) << 2;
        bool cok = c4 < BxA;
        bool g0 = cok & (r0      < By);
        bool g1 = cok & (r0 + 16 < By);
        bool g2 = cok & (r0 + 32 < By);
        bool g3 = cok & (r0 + 48 < By);

        auto burst = [&](const float* s, float* dst, int stride) {
            f4_t t0 = {0,0,0,0}, t1 = {0,0,0,0}, t2 = {0,0,0,0}, t3 = {0,0,0,0};
            if (g0) t0 = *(const f4_t*)(s +  r0       * WW + c4);
            if (g1) t1 = *(const f4_t*)(s + (r0 + 16) * WW + c4);
            if (g2) t2 = *(const f4_t*)(s + (r0 + 32) * WW + c4);
            if (g3) t3 = *(const f4_t*)(s + (r0 + 48) * WW + c4);
            if (g0) *(f4_t*)(dst +  r0       * stride + c4) = t0;
            if (g1) *(f4_t*)(dst + (r0 + 16) * stride + c4) = t1;
            if (g2) *(f4_t*)(dst + (r0 + 32) * stride + c4) = t2;
            if (g3) *(f4_t*)(dst + (r0 + 48) * stride + c4) = t3;
        };

        float ix = ct * (float)w0 - st * (float)h + Cx;
        float iy = st * (float)w0 + ct * (float)h + Cy;

        float al[4], ar[4], f0[4], f1[4];
        int o0[4], o1[4];

        if (interior) {
#pragma unroll
            for (int p = 0; p < 4; ++p) {
                float x0f = floorf(ix), y0f = floorf(iy);
                float fx = ix - x0f,    fy = iy - y0f;
                int x0 = (int)x0f, y0 = (int)y0f;
                al[p] = 1.0f - fx;
                ar[p] = fx;
                f0[p] = 1.0f - fy;
                f1[p] = fy;
                int lx = x0 - ax_lo;
                o0[p] = (y0     - py_lo) * lstr + lx;
                o1[p] = (y0 + 1 - py_lo) * lstr + lx;
                ix += ct;
                iy += st;
            }
        } else {
#pragma unroll
            for (int p = 0; p < 4; ++p) {
                float x0f = floorf(ix), y0f = floorf(iy);
                float fx = ix - x0f,    fy = iy - y0f;
                int x0 = (int)x0f, y0 = (int)y0f;
                int y1 = y0 + 1;

                bool xin = (x0 >= 0) & (x0 <= WW - 2);
                float wl = 1.0f - fx;
                al[p] = xin ? wl : ((x0 == -1)     ? fx : 0.0f);
                ar[p] = xin ? fx : ((x0 == WW - 1) ? wl : 0.0f);
                int base = min(max(x0, 0), WW - 2);

                bool vy0 = (y0 >= 0) & (y0 < HH);
                bool vy1 = (y1 >= 0) & (y1 < HH);
                int y0c = min(max(y0, 0), HH - 1);
                int y1c = min(max(y1, 0), HH - 1);
                f0[p] = (1.0f - fy) * (float)vy0;
                f1[p] = fy          * (float)vy1;

                int lx = base - ax_lo;
                o0[p] = (y0c - py_lo) * lstr + lx;
                o1[p] = (y1c - py_lo) * lstr + lx;
                ix += ct;
                iy += st;
            }
        }

        if (compact) {
            burst(srcb,          &smem[0],       SSTR);
            burst(srcb + HW,     &smem[cpc],     SSTR);
            burst(srcb + 2 * HW, &smem[2 * cpc], SSTR);
            __syncthreads();
#pragma unroll
            for (int ch = 0; ch < CC; ++ch) {
                const float* pl = &smem[ch * cpc];
                f4_t v;
#pragma unroll
                for (int p = 0; p < 4; ++p) {
                    float a0 = pl[o0[p]], a1 = pl[o0[p] + 1];
                    float b0 = pl[o1[p]], b1 = pl[o1[p] + 1];
                    v[p] = f0[p] * (al[p] * a0 + ar[p] * a1)
                         + f1[p] * (al[p] * b0 + ar[p] * b1);
                }
                __builtin_nontemporal_store(v, (f4_t*)(ob + ch * HW));
            }
        } else {
#pragma unroll
            for (int ch = 0; ch < CC; ++ch) {
                if (ch) __syncthreads();
                burst(srcb + ch * HW, smem, PSTRIDE);
                __syncthreads();

                f4_t v;
#pragma unroll
                for (int p = 0; p < 4; ++p) {
                    float a0 = smem[o0[p]], a1 = smem[o0[p] + 1];
                    float b0 = smem[o1[p]], b1 = smem[o1[p] + 1];
                    v[p] = f0[p] * (al[p] * a0 + ar[p] * a1)
                         + f1[p] * (al[p] * b0 + ar[p] * b1);
                }
                __builtin_nontemporal_store(v, (f4_t*)(ob + ch * HW));
            }
        }
        return;
    }

    // ================= SUB-TILE path (large scale) =================
    int rS = tid >> 4;              // 0..15: blend row, staging row base
    int cS = tid & 15;              // 0..15: blend col
    int c4 = cS << 2;               // staging col (floats)

#pragma unroll 1
    for (int s = 0; s < 4; ++s) {
        int sW = tileW + ((s & 1) << 4);
        int sH = tileH + ((s >> 1) << 4);

        float wAs = (float)sW, wBs = (float)(sW + 15);
        float hAs = (float)sH, hBs = (float)(sH + 15);
        float cwAs = ct * wAs, cwBs = ct * wBs, shAs = st * hAs, shBs = st * hBs;
        float ixmn = fminf(cwAs, cwBs) - fmaxf(shAs, shBs) + Cx;
        float ixmx = fmaxf(cwAs, cwBs) - fminf(shAs, shBs) + Cx;
        float swAs = st * wAs, swBs = st * wBs, chAs = ct * hAs, chBs = ct * hBs;
        float iymn = fminf(swAs, swBs) + fminf(chAs, chBs) + Cy;
        float iymx = fmaxf(swAs, swBs) + fmaxf(chAs, chBs) + Cy;

        int bxl = (int)floorf(ixmn) - 1;
        int bxh = (int)floorf(ixmx) + 2;
        int byl = (int)floorf(iymn) - 1;
        int byh = (int)floorf(iymx) + 2;

        int ws = sW + cS;
        int hs = sH + rS;
        float* ob2 = out + b * CHW + hs * WW + ws;

        bool oob_s = (bxh <= 0) | (bxl >= WW - 1) | (byh <= 0) | (byl >= HH - 1);
        if (oob_s) {
#pragma unroll
            for (int ch = 0; ch < CC; ++ch)
                __builtin_nontemporal_store(0.0f, ob2 + ch * HW);
            continue;
        }

        int pxl = min(max(bxl, 0), WW - 2);
        int pxh = min(max(bxh - 1, 0), WW - 2) + 1;
        int pyl = min(max(byl, 0), HH - 2);
        int pyh = min(max(byh - 1, 0), HH - 2) + 1;
        int Bys = pyh - pyl + 1;

        int axl = pxl & ~3;
        int spn = pxh - axl;
        bool subok = (spn <= 63) && (Bys <= PROWS);
        int BxS = (spn | 3) + 1;
        if (axl + BxS > WW) axl = WW - BxS;

        float ixs = ct * (float)ws - st * (float)hs + Cx;
        float iys = st * (float)ws + ct * (float)hs + Cy;
        float x0f = floorf(ixs), y0f = floorf(iys);
        float fxs = ixs - x0f,   fys = iys - y0f;
        int x0 = (int)x0f, y0 = (int)y0f;
        int y1 = y0 + 1;

        bool xin = (x0 >= 0) & (x0 <= WW - 2);
        float wl = 1.0f - fxs;
        float alS = xin ? wl  : ((x0 == -1)     ? fxs : 0.0f);
        float arS = xin ? fxs : ((x0 == WW - 1) ? wl  : 0.0f);
        int base = min(max(x0, 0), WW - 2);

        bool vy0 = (y0 >= 0) & (y0 < HH);
        bool vy1 = (y1 >= 0) & (y1 < HH);
        int y0c = min(max(y0, 0), HH - 1);
        int y1c = min(max(y1, 0), HH - 1);
        float f0S = (1.0f - fys) * (float)vy0;
        float f1S = fys          * (float)vy1;

        if (subok) {
            int lx  = base - axl;
            int os0 = (y0c - pyl) * PSTRIDE + lx;
            int os1 = (y1c - pyl) * PSTRIDE + lx;
            const float* sb = plane0 + pyl * WW + axl;

            bool cokS = c4 < BxS;
            bool h0 = cokS & (rS      < Bys);
            bool h1 = cokS & (rS + 16 < Bys);
            bool h2 = cokS & (rS + 32 < Bys);
            bool h3 = cokS & (rS + 48 < Bys);

            for (int ch = 0; ch < CC; ++ch) {
                __syncthreads();
                {
                    const float* ss = sb + ch * HW;
                    f4_t t0 = {0,0,0,0}, t1 = {0,0,0,0}, t2 = {0,0,0,0}, t3 = {0,0,0,0};
                    if (h0) t0 = *(const f4_t*)(ss +  rS       * WW + c4);
                    if (h1) t1 = *(const f4_t*)(ss + (rS + 16) * WW + c4);
                    if (h2) t2 = *(const f4_t*)(ss + (rS + 32) * WW + c4);
                    if (h3) t3 = *(const f4_t*)(ss + (rS + 48) * WW + c4);
                    if (h0) *(f4_t*)(&smem[ rS       * PSTRIDE + c4]) = t0;
                    if (h1) *(f4_t*)(&smem[(rS + 16) * PSTRIDE + c4]) = t1;
                    if (h2) *(f4_t*)(&smem[(rS + 32) * PSTRIDE + c4]) = t2;
                    if (h3) *(f4_t*)(&smem[(rS + 48) * PSTRIDE + c4]) = t3;
                }
                __syncthreads();

                float a0 = smem[os0], a1 = smem[os0 + 1];
                float b0 = smem[os1], b1 = smem[os1 + 1];
                float v = f0S * (alS * a0 + arS * a1)
                        + f1S * (alS * b0 + arS * b1);
                __builtin_nontemporal_store(v, ob2 + ch * HW);
            }
        } else {
            int og0 = y0c * WW + base;
            int og1 = y1c * WW + base;
#pragma unroll
            for (int ch = 0; ch < CC; ++ch) {
                const float* pl = plane0 + ch * HW;
                f2_t t = *(const f2_t*)(pl + og0);
                f2_t u = *(const f2_t*)(pl + og1);
                float v = f0S * (alS * t.x + arS * t.y)
                        + f1S * (alS * u.x + arS * u.y);
                __builtin_nontemporal_store(v, ob2 + ch * HW);
            }
        }
    }
}

extern "C" void kernel_launch(void* const* d_in, const int* in_sizes, int n_in,
                              void* d_out, int out_size, void* d_ws, size_t ws_size,
                              hipStream_t stream)
{
    const float* x  = (const float*)d_in[0];
    const float* mp = (const float*)d_in[1];
    float* out = (float*)d_out;

    dim3 block(256);
    dim3 grid(BB * 256);            // 64 batches x 16x16 tiles of 32x32
    affine_sample_kernel<<<grid, block, 0, stream>>>(x, mp, out);
}